// Round 1
// baseline (338.738 us; speedup 1.0000x reference)
//
#include <hip/hip_runtime.h>

#define BB 32
#define IDF 64
#define RESX 128
#define QL (RESX * RESX)   // 16384
#define CDF 768
#define SL 18
#define SLP 20             // padded row stride for sourceT / v
#define ADIM 100

// ---------------- Kernel 1: sourceT = conv_ctx_w @ context[b], plus v = conv_w . sourceT
// grid = (32), block = 1024 (16 waves). Each wave computes 4 rows (i) of the 64x18 result.
__global__ __launch_bounds__(1024) void k1_source(
        const float* __restrict__ ctx,      // [B, CDF, SL]
        const float* __restrict__ wic,      // [IDF, CDF]
        const float* __restrict__ conv_w,   // [IDF]
        float* __restrict__ sT,             // ws: [B, IDF, SLP]
        float* __restrict__ v)              // ws: [B, SLP]
{
    __shared__ float ctx_l[CDF * 19];      // padded: bank-conflict-free (58368 B)
    __shared__ float sT_l[IDF * SLP];      // 5120 B
    const int b = blockIdx.x;
    const float* ctxb = ctx + (size_t)b * CDF * SL;

    for (int t = threadIdx.x; t < CDF * SL; t += 1024) {
        int c = t / SL;
        int s = t - c * SL;
        ctx_l[c * 19 + s] = ctxb[t];
    }
    __syncthreads();

    const int wave = threadIdx.x >> 6;
    const int lane = threadIdx.x & 63;

    for (int ii = 0; ii < 4; ii++) {
        const int i = wave * 4 + ii;
        float acc[SL];
#pragma unroll
        for (int s = 0; s < SL; s++) acc[s] = 0.f;

        for (int k = 0; k < CDF / 64; k++) {
            const int c = k * 64 + lane;
            const float wv = wic[i * CDF + c];   // coalesced across lanes
#pragma unroll
            for (int s = 0; s < SL; s++) acc[s] += wv * ctx_l[c * 19 + s];
        }
        // butterfly reduce each of the 18 partials across the 64 lanes
#pragma unroll
        for (int s = 0; s < SL; s++) {
            float a = acc[s];
            for (int off = 32; off; off >>= 1) a += __shfl_xor(a, off, 64);
            acc[s] = a;
        }
        if (lane == 0) {
#pragma unroll
            for (int s = 0; s < SL; s++) {
                sT[(size_t)b * IDF * SLP + i * SLP + s] = acc[s];
                sT_l[i * SLP + s] = acc[s];
            }
        }
    }
    __syncthreads();
    if (threadIdx.x < SL) {
        const int s = threadIdx.x;
        float a = 0.f;
        for (int i = 0; i < IDF; i++) a += conv_w[i] * sT_l[i * SLP + s];
        v[b * SLP + s] = a;
    }
}

// ---------------- Kernel 2: per-query scores -> softmax -> dot with v. HBM-bound main pass.
// grid = (QL/256, B), block = 256. One thread per query.
__global__ __launch_bounds__(256) void k2_attn(
        const float* __restrict__ inp,     // [B, IDF, QL]
        const float* __restrict__ sT,      // [B, IDF, SLP]
        const float* __restrict__ v,       // [B, SLP]
        const float* __restrict__ conv_b,  // [1]
        float* __restrict__ wq)            // ws: [B, QL]
{
    const int b = blockIdx.y;
    const int q = blockIdx.x * 256 + threadIdx.x;
    const float* ip = inp + (size_t)b * IDF * QL + q;
    const float* st = sT + (size_t)b * IDF * SLP;   // wave-uniform address stream -> SGPRs

    float sc[SL];
#pragma unroll
    for (int s = 0; s < SL; s++) sc[s] = 0.f;

#pragma unroll 4
    for (int i = 0; i < IDF; i++) {
        const float x = ip[(size_t)i * QL];         // coalesced: lanes = consecutive q
#pragma unroll
        for (int s = 0; s < SL; s++) sc[s] += x * st[i * SLP + s];
    }

    float m = sc[0];
#pragma unroll
    for (int s = 1; s < SL; s++) m = fmaxf(m, sc[s]);

    const float* vb = v + b * SLP;
    float l = 0.f, acc = 0.f;
#pragma unroll
    for (int s = 0; s < SL; s++) {
        const float p = __expf(sc[s] - m);
        l += p;
        acc += p * vb[s];
    }
    wq[(size_t)b * QL + q] = acc / l + conv_b[0];
}

// ---------------- Kernel 3a: out[b,a] = fc_b[a]
__global__ __launch_bounds__(256) void k3a_init(const float* __restrict__ fc_b,
                                                float* __restrict__ out)
{
    const int idx = blockIdx.x * 256 + threadIdx.x;
    if (idx < BB * ADIM) out[idx] = fc_b[idx % ADIM];
}

// ---------------- Kernel 3: out[b,a] += sum_q wq[b,q] * fc_w[a,q]  (chunked over q, atomic)
// grid = (QL/64) = 256 blocks, block = 256.
#define CHK 64
#define CHKP 65   // padded LDS stride (65 % 32 == 1 -> conflict-free)
__global__ __launch_bounds__(256) void k3_fc(
        const float* __restrict__ wq,      // [B, QL]
        const float* __restrict__ fcw,     // [ADIM, QL]
        float* __restrict__ out)           // [B, ADIM]
{
    __shared__ float wl[BB * CHKP];        // 8320 B
    __shared__ float fl[ADIM * CHKP];      // 26000 B
    const int q0 = blockIdx.x * CHK;

    for (int t = threadIdx.x; t < BB * CHK; t += 256) {
        const int bb = t >> 6, k = t & (CHK - 1);
        wl[bb * CHKP + k] = wq[(size_t)bb * QL + q0 + k];
    }
    for (int t = threadIdx.x; t < ADIM * CHK; t += 256) {
        const int a = t >> 6, k = t & (CHK - 1);
        fl[a * CHKP + k] = fcw[(size_t)a * QL + q0 + k];
    }
    __syncthreads();

    for (int o = threadIdx.x; o < BB * ADIM; o += 256) {
        const int bb = o / ADIM;
        const int a = o - bb * ADIM;
        float acc = 0.f;
#pragma unroll 8
        for (int k = 0; k < CHK; k++) acc += wl[bb * CHKP + k] * fl[a * CHKP + k];
        atomicAdd(&out[bb * ADIM + a], acc);
    }
}

extern "C" void kernel_launch(void* const* d_in, const int* in_sizes, int n_in,
                              void* d_out, int out_size, void* d_ws, size_t ws_size,
                              hipStream_t stream)
{
    const float* inputs     = (const float*)d_in[0];  // [32,64,128,128]
    const float* context    = (const float*)d_in[1];  // [32,768,18]
    const float* conv_ctx_w = (const float*)d_in[2];  // [64,768]
    const float* conv_w     = (const float*)d_in[3];  // [64]
    const float* conv_b     = (const float*)d_in[4];  // [1]
    const float* fc_w       = (const float*)d_in[5];  // [100,16384]
    const float* fc_b       = (const float*)d_in[6];  // [100]
    float* out = (float*)d_out;

    float* ws = (float*)d_ws;
    float* sT = ws;                       // 32*64*20 = 40960 floats
    float* v  = ws + (size_t)BB * IDF * SLP;          // +40960, 640 floats
    float* wq = v + (size_t)BB * SLP;                 // +41600, 524288 floats (~2.2 MB total)

    k1_source<<<dim3(BB), dim3(1024), 0, stream>>>(context, conv_ctx_w, conv_w, sT, v);
    k2_attn<<<dim3(QL / 256, BB), dim3(256), 0, stream>>>(inputs, sT, v, conv_b, wq);
    k3a_init<<<dim3((BB * ADIM + 255) / 256), dim3(256), 0, stream>>>(fc_b, out);
    k3_fc<<<dim3(QL / CHK), dim3(256), 0, stream>>>(wq, fc_w, out);
}

// Round 3
// 258.992 us; speedup vs baseline: 1.3079x; 1.3079x over previous
//
#include <hip/hip_runtime.h>

#define BB 32
#define IDF 64
#define QL 16384
#define CDF 768
#define SL 18
#define SLP 20             // padded row stride for ctx_l / sT
#define ADIM 100

__device__ __forceinline__ void fma4(float4& a, const float4 v, const float s) {
    a.x += v.x * s; a.y += v.y * s; a.z += v.z * s; a.w += v.w * s;
}

// ---------------- Kernel 1: sT[b,i,s] = sum_c wic[i,c] * ctx[b,c,s]
// grid = (32, 4), block = 256 (4 waves). Block (b,g): rows i in [16g, 16g+16).
__global__ __launch_bounds__(256, 2) void k1_source(
        const float* __restrict__ ctx,      // [B, CDF, SL]
        const float* __restrict__ wic,      // [IDF, CDF]
        float* __restrict__ sT)             // ws: [B, IDF, SLP]
{
    __shared__ __align__(16) float ctx_l[CDF * SLP];   // 61440 B
    const int b = blockIdx.x;
    const int g = blockIdx.y;
    const float* ctxb = ctx + (size_t)b * CDF * SL;

    for (int t = threadIdx.x; t < CDF * SL; t += 256) {
        const int c = t / SL;
        const int s = t - c * SL;
        ctx_l[c * SLP + s] = ctxb[t];
    }
    __syncthreads();

    const int wave = threadIdx.x >> 6;
    const int lane = threadIdx.x & 63;

    for (int ii = 0; ii < 4; ii++) {
        const int i = g * 16 + wave * 4 + ii;
        float acc[SL];
#pragma unroll
        for (int s = 0; s < SL; s++) acc[s] = 0.f;

        for (int k = 0; k < CDF / 64; k++) {
            const int c = k * 64 + lane;
            const float wv = wic[i * CDF + c];             // coalesced
            float r[SLP];
            const float4* r4 = (const float4*)&ctx_l[c * SLP];
            ((float4*)r)[0] = r4[0];
            ((float4*)r)[1] = r4[1];
            ((float4*)r)[2] = r4[2];
            ((float4*)r)[3] = r4[3];
            ((float4*)r)[4] = r4[4];
#pragma unroll
            for (int s = 0; s < SL; s++) acc[s] += wv * r[s];
        }
#pragma unroll
        for (int s = 0; s < SL; s++) {
            float a = acc[s];
#pragma unroll
            for (int off = 32; off; off >>= 1) a += __shfl_xor(a, off, 64);
            if (lane == 0) sT[((size_t)b * IDF + i) * SLP + s] = a;
        }
    }
}

// ---------------- Kernel 2: scores -> softmax -> dot with v.  HBM-bound main pass.
// grid = (16, 32), block = 256. Each thread: 4 consecutive q (float4 stream).
__global__ __launch_bounds__(256, 2) void k2_attn(
        const float* __restrict__ inp,     // [B, IDF, QL]
        const float* __restrict__ sT,      // [B, IDF, SLP]
        const float* __restrict__ conv_w,  // [IDF]
        const float* __restrict__ conv_b,  // [1]
        float* __restrict__ wq)            // ws: [B, QL]
{
    __shared__ __align__(16) float st_l[IDF * SLP];   // 5120 B
    __shared__ float cw_l[IDF];
    __shared__ float v_l[SL];
    const int b = blockIdx.y;
    const int tid = threadIdx.x;

    for (int t = tid; t < IDF * SLP; t += 256) st_l[t] = sT[(size_t)b * IDF * SLP + t];
    if (tid < IDF) cw_l[tid] = conv_w[tid];
    __syncthreads();
    if (tid < SL) {
        float a = 0.f;
#pragma unroll
        for (int i = 0; i < IDF; i++) a += cw_l[i] * st_l[i * SLP + tid];
        v_l[tid] = a;
    }
    __syncthreads();

    const int q = (blockIdx.x * 256 + tid) * 4;
    const float4* ip4 = (const float4*)(inp + (size_t)b * IDF * QL + q);

    float4 sc[SL];
#pragma unroll
    for (int s = 0; s < SL; s++) sc[s] = make_float4(0.f, 0.f, 0.f, 0.f);

#pragma unroll 4
    for (int i = 0; i < IDF; i++) {
        const float4 x = ip4[i * (QL / 4)];               // coalesced 16B/lane
        float r[SLP];
        const float4* r4 = (const float4*)&st_l[i * SLP]; // wave-uniform -> LDS broadcast
        ((float4*)r)[0] = r4[0];
        ((float4*)r)[1] = r4[1];
        ((float4*)r)[2] = r4[2];
        ((float4*)r)[3] = r4[3];
        ((float4*)r)[4] = r4[4];
#pragma unroll
        for (int s = 0; s < SL; s++) fma4(sc[s], x, r[s]);
    }

    float4 m = sc[0];
#pragma unroll
    for (int s = 1; s < SL; s++) {
        m.x = fmaxf(m.x, sc[s].x); m.y = fmaxf(m.y, sc[s].y);
        m.z = fmaxf(m.z, sc[s].z); m.w = fmaxf(m.w, sc[s].w);
    }
    float4 l = make_float4(0.f, 0.f, 0.f, 0.f);
    float4 o = make_float4(0.f, 0.f, 0.f, 0.f);
#pragma unroll
    for (int s = 0; s < SL; s++) {
        const float vs = v_l[s];
        float4 p;
        p.x = __expf(sc[s].x - m.x); p.y = __expf(sc[s].y - m.y);
        p.z = __expf(sc[s].z - m.z); p.w = __expf(sc[s].w - m.w);
        l.x += p.x; l.y += p.y; l.z += p.z; l.w += p.w;
        o.x += p.x * vs; o.y += p.y * vs; o.z += p.z * vs; o.w += p.w * vs;
    }
    const float cb = conv_b[0];
    float4 res;
    res.x = o.x / l.x + cb; res.y = o.y / l.y + cb;
    res.z = o.z / l.z + cb; res.w = o.w / l.w + cb;
    ((float4*)(wq + (size_t)b * QL))[blockIdx.x * 256 + tid] = res;
}

// ---------------- Kernel 3a: out[b,a] = fc_b[a]
__global__ __launch_bounds__(256) void k3a_init(const float* __restrict__ fc_b,
                                                float* __restrict__ out)
{
    const int idx = blockIdx.x * 256 + threadIdx.x;
    if (idx < BB * ADIM) out[idx] = fc_b[idx % ADIM];
}

// ---------------- Kernel 3: out[b,a] += sum_q wq[b,q] * fc_w[a,q]
// Wave-per-(4b x 4a x 2048q) register tile; coalesced float4 reads; butterfly
// reduce; 8 atomics per output address total (no contention).
__global__ __launch_bounds__(256) void k3_fc(
        const float* __restrict__ wq,      // [B, QL]
        const float* __restrict__ fcw,     // [ADIM, QL]
        float* __restrict__ out)           // [B, ADIM]
{
    const int w = blockIdx.x * 4 + (threadIdx.x >> 6);   // 1600 waves
    const int lane = threadIdx.x & 63;
    const int b4 = w / 200;
    const int rem = w - b4 * 200;
    const int ag = rem >> 3;          // 0..24
    const int qc = rem & 7;           // 0..7
    const int b0 = b4 * 4, a0 = ag * 4, q0 = qc * 2048;

    float4 acc[4][4];
#pragma unroll
    for (int i = 0; i < 4; i++)
#pragma unroll
        for (int j = 0; j < 4; j++) acc[i][j] = make_float4(0.f, 0.f, 0.f, 0.f);

#pragma unroll 2
    for (int k = 0; k < 8; k++) {
        const int qi = q0 + (k * 64 + lane) * 4;
        float4 wv[4], fv[4];
#pragma unroll
        for (int i = 0; i < 4; i++) wv[i] = *(const float4*)(wq + (size_t)(b0 + i) * QL + qi);
#pragma unroll
        for (int j = 0; j < 4; j++) fv[j] = *(const float4*)(fcw + (size_t)(a0 + j) * QL + qi);
#pragma unroll
        for (int i = 0; i < 4; i++) {
#pragma unroll
            for (int j = 0; j < 4; j++) {
                acc[i][j].x += wv[i].x * fv[j].x;
                acc[i][j].y += wv[i].y * fv[j].y;
                acc[i][j].z += wv[i].z * fv[j].z;
                acc[i][j].w += wv[i].w * fv[j].w;
            }
        }
    }

#pragma unroll
    for (int i = 0; i < 4; i++) {
#pragma unroll
        for (int j = 0; j < 4; j++) {
            float r = acc[i][j].x + acc[i][j].y + acc[i][j].z + acc[i][j].w;
#pragma unroll
            for (int off = 32; off; off >>= 1) r += __shfl_xor(r, off, 64);
            if (lane == 0) atomicAdd(&out[(b0 + i) * ADIM + a0 + j], r);
        }
    }
}

extern "C" void kernel_launch(void* const* d_in, const int* in_sizes, int n_in,
                              void* d_out, int out_size, void* d_ws, size_t ws_size,
                              hipStream_t stream)
{
    const float* inputs     = (const float*)d_in[0];  // [32,64,128,128]
    const float* context    = (const float*)d_in[1];  // [32,768,18]
    const float* conv_ctx_w = (const float*)d_in[2];  // [64,768]
    const float* conv_w     = (const float*)d_in[3];  // [64]
    const float* conv_b     = (const float*)d_in[4];  // [1]
    const float* fc_w       = (const float*)d_in[5];  // [100,16384]
    const float* fc_b       = (const float*)d_in[6];  // [100]
    float* out = (float*)d_out;

    float* ws = (float*)d_ws;
    float* sT = ws;                                   // 32*64*20 = 40960 floats
    float* wq = ws + (size_t)BB * IDF * SLP;          // 524288 floats

    k1_source<<<dim3(BB, 4), dim3(256), 0, stream>>>(context, conv_ctx_w, sT);
    k2_attn<<<dim3(QL / 1024, BB), dim3(256), 0, stream>>>(inputs, sT, conv_w, conv_b, wq);
    k3a_init<<<dim3((BB * ADIM + 255) / 256), dim3(256), 0, stream>>>(fc_b, out);
    k3_fc<<<dim3(400), dim3(256), 0, stream>>>(wq, fc_w, out);
}